// Round 13
// baseline (279.601 us; speedup 1.0000x reference)
//
#include <hip/hip_runtime.h>
#include <hip/hip_bf16.h>
#include <cstdint>

typedef __attribute__((ext_vector_type(4))) float f32x4;
typedef __attribute__((ext_vector_type(16))) float f32x16;
typedef __attribute__((ext_vector_type(8))) short bf16x8;
typedef __attribute__((ext_vector_type(4))) unsigned int u32x4;
typedef unsigned short u16;
typedef unsigned int u32;

__device__ __forceinline__ u16 f2b(float x) {
  __hip_bfloat16 h = __float2bfloat16(x);
  return *reinterpret_cast<u16*>(&h);
}

__device__ __forceinline__ u32 pk(float a, float b) {
  __hip_bfloat162 h2 = __float22bfloat162_rn(float2{a, b});
  return *reinterpret_cast<u32*>(&h2);
}

__device__ __forceinline__ void gload16(const void* g, void* l) {
  __builtin_amdgcn_global_load_lds((const __attribute__((address_space(1))) u32*)g,
                                   (__attribute__((address_space(3))) u32*)l, 16, 0, 0);
}

__device__ __forceinline__ float xmax32(float x) {
  return fmaxf(x, __shfl_xor(x, 32, 64));
}
__device__ __forceinline__ float xsum32(float x) {
  return x + __shfl_xor(x, 32, 64);
}

// ---------------- converts ----------------

__global__ void cvt_f32_bf16(const float* __restrict__ in, u16* __restrict__ out, int n4) {
  int idx = (blockIdx.x * 256 + threadIdx.x);
  if (idx < n4) {
    const float4 v = *(const float4*)(in + (size_t)idx * 4);
    u16* o = out + (size_t)idx * 4;
    o[0] = f2b(v.x); o[1] = f2b(v.y); o[2] = f2b(v.z); o[3] = f2b(v.w);
  }
}

// merged: wq|wk|wv -> wqkv_t (by<96) and wo -> wo_t (by>=96)
__global__ void w_transpose_all(const float* __restrict__ wq, const float* __restrict__ wk,
                                const float* __restrict__ wv, const float* __restrict__ wo,
                                u16* __restrict__ wqkv_t, u16* __restrict__ wo_t) {
  __shared__ float tile[32][33];
  int k0 = blockIdx.x * 32;
  int by = blockIdx.y;
  const float* src; int srcN; int c0; u16* out; int n0;
  if (by < 96) {
    n0 = by * 32; out = wqkv_t;
    if (n0 < 2048)      { src = wq; srcN = 2048; c0 = n0; }
    else if (n0 < 2560) { src = wk; srcN = 512;  c0 = n0 - 2048; }
    else                { src = wv; srcN = 512;  c0 = n0 - 2560; }
  } else {
    n0 = (by - 96) * 32; out = wo_t; src = wo; srcN = 2048; c0 = n0;
  }
  int tx = threadIdx.x & 31, ty = threadIdx.x >> 5;
#pragma unroll
  for (int j = 0; j < 32; j += 8)
    tile[ty + j][tx] = src[(size_t)(k0 + ty + j) * srcN + c0 + tx];
  __syncthreads();
#pragma unroll
  for (int j = 0; j < 32; j += 8)
    out[(size_t)(n0 + ty + j) * 2048 + k0 + tx] = f2b(tile[tx][ty + j]);
}

// ---------------- GEMM 256x256 (counted-vmcnt) + fused bias/RoPE/V-transpose epilogue ----------------
// QKV projection. Q cols (<2048): bias+RoPE+scale -> qkv bf16.
// K cols (2048..2559): bias+RoPE -> qkv bf16.
// V cols (>=2560): bias -> vt transposed (d-major), qkv untouched.
// Column-blocks are uniform per branch (n0 multiples of 256).
__global__ __launch_bounds__(512, 2) void gemm256_bt(
    const u16* __restrict__ A, const u16* __restrict__ Bt,
    const float* __restrict__ bq, const float* __restrict__ bk,
    const float* __restrict__ bv, u16* __restrict__ C,
    u16* __restrict__ vt, int M, int N, int K, int gx) {
  __shared__ u16 lds[65536];   // 131072 B
  const int tid = threadIdx.x, lane = tid & 63;
  const int w = tid >> 6, wr = w >> 2, wc = w & 3;
  const int nb = gridDim.x;
  const int swz = (blockIdx.x & 7) * (nb >> 3) + (blockIdx.x >> 3);
  const int m0 = (swz / gx) * 256, n0 = (swz % gx) * 256;
  const int l15 = lane & 15;
  const int gx16 = ((lane >> 4) * 16) ^ (((l15 >> 1) & 3) << 4);  // read byte-off (lane-const)

#define GL(X, kh, bufi, t)                                                      \
  { _Pragma("unroll")                                                           \
    for (int rd = 0; rd < 2; ++rd) {                                            \
      int c = tid + rd * 512;                                                   \
      int row = c >> 2;                                                         \
      int sx = ((c & 3) * 16) ^ (((row >> 1) & 3) << 4);                        \
      const u16* srcp = ((X) ? Bt + (size_t)(n0 + row) * K                      \
                             : A + (size_t)(m0 + row) * K) + (t) * 64 + (kh) * 32; \
      gload16((const char*)srcp + sx,                                           \
              (char*)lds + (bufi) * 65536 + (X) * 32768 + (kh) * 16384 + c * 16); \
    } }

  f32x4 acc[8][4] = {};
  const int NT = K >> 6;

  GL(0, 0, 0, 0) GL(1, 0, 0, 0) GL(0, 1, 0, 0) GL(1, 1, 0, 0)

  for (int t = 0; t < NT; ++t) {
    const int buf = t & 1, nbuf = buf ^ 1;
    const int tn = (t + 1 < NT) ? t + 1 : NT - 1;
    const char* Ab = (const char*)lds + buf * 65536;
    const char* Bb = Ab + 32768;
    bf16x8 af[4], bfr[4];

    // ---- phase 1: K-half 0, m0-3
    asm volatile("s_waitcnt vmcnt(4)" ::: "memory");
    __builtin_amdgcn_s_barrier();
    GL(0, 0, nbuf, tn)
#pragma unroll
    for (int n = 0; n < 4; ++n)
      bfr[n] = *(const bf16x8*)(Bb + (wc * 64 + n * 16 + l15) * 64 + gx16);
#pragma unroll
    for (int m = 0; m < 4; ++m)
      af[m] = *(const bf16x8*)(Ab + (wr * 128 + m * 16 + l15) * 64 + gx16);
    __builtin_amdgcn_s_setprio(1);
#pragma unroll
    for (int m = 0; m < 4; ++m)
#pragma unroll
      for (int n = 0; n < 4; ++n)
        acc[m][n] = __builtin_amdgcn_mfma_f32_16x16x32_bf16(af[m], bfr[n], acc[m][n], 0, 0, 0);
    __builtin_amdgcn_s_setprio(0);

    // ---- phase 2: K-half 0, m4-7
    GL(1, 0, nbuf, tn)
#pragma unroll
    for (int m = 0; m < 4; ++m)
      af[m] = *(const bf16x8*)(Ab + (wr * 128 + (m + 4) * 16 + l15) * 64 + gx16);
    __builtin_amdgcn_s_setprio(1);
#pragma unroll
    for (int m = 0; m < 4; ++m)
#pragma unroll
      for (int n = 0; n < 4; ++n)
        acc[m + 4][n] = __builtin_amdgcn_mfma_f32_16x16x32_bf16(af[m], bfr[n], acc[m + 4][n], 0, 0, 0);
    __builtin_amdgcn_s_setprio(0);

    // ---- phase 3: K-half 1, m0-3
    asm volatile("s_waitcnt vmcnt(4)" ::: "memory");
    __builtin_amdgcn_s_barrier();
    GL(0, 1, nbuf, tn)
#pragma unroll
    for (int n = 0; n < 4; ++n)
      bfr[n] = *(const bf16x8*)(Bb + 16384 + (wc * 64 + n * 16 + l15) * 64 + gx16);
#pragma unroll
    for (int m = 0; m < 4; ++m)
      af[m] = *(const bf16x8*)(Ab + 16384 + (wr * 128 + m * 16 + l15) * 64 + gx16);
    __builtin_amdgcn_s_setprio(1);
#pragma unroll
    for (int m = 0; m < 4; ++m)
#pragma unroll
      for (int n = 0; n < 4; ++n)
        acc[m][n] = __builtin_amdgcn_mfma_f32_16x16x32_bf16(af[m], bfr[n], acc[m][n], 0, 0, 0);
    __builtin_amdgcn_s_setprio(0);

    // ---- phase 4: K-half 1, m4-7
    GL(1, 1, nbuf, tn)
#pragma unroll
    for (int m = 0; m < 4; ++m)
      af[m] = *(const bf16x8*)(Ab + 16384 + (wr * 128 + (m + 4) * 16 + l15) * 64 + gx16);
    __builtin_amdgcn_s_setprio(1);
#pragma unroll
    for (int m = 0; m < 4; ++m)
#pragma unroll
      for (int n = 0; n < 4; ++n)
        acc[m + 4][n] = __builtin_amdgcn_mfma_f32_16x16x32_bf16(af[m], bfr[n], acc[m + 4][n], 0, 0, 0);
    __builtin_amdgcn_s_setprio(0);
  }
  asm volatile("s_waitcnt vmcnt(0)" ::: "memory");

  // ---- fused epilogue ----
  const int colbase = n0 + wc * 64;
  if (n0 < 2560) {
    // Q or K: bias + RoPE (+ scale for Q), write bf16 to qkv
    const float qscale = (n0 < 2048) ? 0.08838834764831845f : 1.0f;
    const bool evenp = !(l15 & 1);
    float theta[4];
#pragma unroll
    for (int n = 0; n < 4; ++n) {
      int col = colbase + n * 16 + l15;
      theta[n] = expf(-(float)((col & 127) >> 1) * 0.14391156831212787f);  // ln(10000)/64
    }
#pragma unroll
    for (int m = 0; m < 8; ++m) {
      int row = m0 + wr * 128 + m * 16 + ((lane >> 4) << 2);
#pragma unroll
      for (int n = 0; n < 4; ++n) {
        int col = colbase + n * 16 + l15;
        float bvv = (col < 2048) ? bq[col] : bk[col - 2048];
        u16* cp = C + (size_t)row * N + col;
#pragma unroll
        for (int r = 0; r < 4; ++r) {
          float v = acc[m][n][r] + bvv;
          float o = __shfl_xor(v, 1, 64);
          float ang = (float)((row + r) & 2047) * theta[n];
          float sn, cs;
          sincosf(ang, &sn, &cs);
          float res = evenp ? (v * cs - o * sn) : (v * cs + o * sn);
          cp[(size_t)r * N] = f2b(res * qscale);
        }
      }
    }
  } else {
    // V: bias, write transposed into vt (d-major); qkv untouched
#pragma unroll
    for (int m = 0; m < 8; ++m) {
      int row = m0 + wr * 128 + m * 16 + ((lane >> 4) << 2);
      int b = row >> 11, s = row & 2047;
#pragma unroll
      for (int n = 0; n < 4; ++n) {
        int col = colbase + n * 16 + l15;
        int c = col - 2560;
        float bvv = bv[c];
        u16* vp = vt + ((size_t)(b * 4 + (c >> 7)) * 128 + (c & 127)) * 2048 + s;
        ushort4 st;
        st.x = f2b(acc[m][n][0] + bvv);
        st.y = f2b(acc[m][n][1] + bvv);
        st.z = f2b(acc[m][n][2] + bvv);
        st.w = f2b(acc[m][n][3] + bvv);
        *(ushort4*)vp = st;
      }
    }
  }
}

// ---------------- GEMM 128x256 2-phase (counted-vmcnt): out projection ----------------
__global__ __launch_bounds__(512, 1) void gemm128x256_bt(
    const u16* __restrict__ A, const u16* __restrict__ Bt,
    float* __restrict__ C, int M, int N, int K, int gx) {
  __shared__ u16 lds[49152];   // 98304 B
  const int tid = threadIdx.x, lane = tid & 63;
  const int w = tid >> 6, wr = w >> 2, wc = w & 3;
  const int nb = gridDim.x;
  const int swz = (blockIdx.x & 7) * (nb >> 3) + (blockIdx.x >> 3);
  const int m0 = (swz / gx) * 128, n0 = (swz % gx) * 256;
  const int l15 = lane & 15;
  const int gx16 = ((lane >> 4) * 16) ^ (((l15 >> 1) & 3) << 4);

#define GLA(kh, bufi, t)                                                        \
  { int c = tid;                                                                \
    int row = c >> 2;                                                           \
    int sx = ((c & 3) * 16) ^ (((row >> 1) & 3) << 4);                          \
    const u16* srcp = A + (size_t)(m0 + row) * K + (t) * 64 + (kh) * 32;        \
    gload16((const char*)srcp + sx,                                             \
            (char*)lds + (bufi) * 16384 + (kh) * 8192 + c * 16); }

#define GLB(kh, bufi, t)                                                        \
  { _Pragma("unroll")                                                           \
    for (int rd = 0; rd < 2; ++rd) {                                            \
      int c = tid + rd * 512;                                                   \
      int row = c >> 2;                                                         \
      int sx = ((c & 3) * 16) ^ (((row >> 1) & 3) << 4);                        \
      const u16* srcp = Bt + (size_t)(n0 + row) * K + (t) * 64 + (kh) * 32;     \
      gload16((const char*)srcp + sx,                                           \
              (char*)lds + 32768 + (bufi) * 32768 + (kh) * 16384 + c * 16); } }

  f32x4 acc[4][4] = {};
  const int NT = K >> 6;

  GLA(0, 0, 0) GLB(0, 0, 0) GLA(1, 0, 0) GLB(1, 0, 0)

  for (int t = 0; t < NT; ++t) {
    const int buf = t & 1, nbuf = buf ^ 1;
    const int tn = (t + 1 < NT) ? t + 1 : NT - 1;
    const char* Ab = (const char*)lds + buf * 16384;
    const char* Bb = (const char*)lds + 32768 + buf * 32768;
    bf16x8 af[4], bfr[4];

#pragma unroll
    for (int kh = 0; kh < 2; ++kh) {
      asm volatile("s_waitcnt vmcnt(3)" ::: "memory");
      __builtin_amdgcn_s_barrier();
      if (kh == 0) { GLA(0, nbuf, tn) GLB(0, nbuf, tn) }
      else         { GLA(1, nbuf, tn) GLB(1, nbuf, tn) }
#pragma unroll
      for (int n = 0; n < 4; ++n)
        bfr[n] = *(const bf16x8*)(Bb + kh * 16384 + (wc * 64 + n * 16 + l15) * 64 + gx16);
#pragma unroll
      for (int m = 0; m < 4; ++m)
        af[m] = *(const bf16x8*)(Ab + kh * 8192 + (wr * 64 + m * 16 + l15) * 64 + gx16);
      __builtin_amdgcn_s_setprio(1);
#pragma unroll
      for (int m = 0; m < 4; ++m)
#pragma unroll
        for (int n = 0; n < 4; ++n)
          acc[m][n] = __builtin_amdgcn_mfma_f32_16x16x32_bf16(af[m], bfr[n], acc[m][n], 0, 0, 0);
      __builtin_amdgcn_s_setprio(0);
    }
  }
  asm volatile("s_waitcnt vmcnt(0)" ::: "memory");

#pragma unroll
  for (int m = 0; m < 4; ++m) {
    int row = m0 + wr * 64 + m * 16 + ((lane >> 4) << 2);
#pragma unroll
    for (int n = 0; n < 4; ++n) {
      int col = n0 + wc * 64 + n * 16 + l15;
      float* cp = C + (size_t)row * N + col;
#pragma unroll
      for (int r = 0; r < 4; ++r) cp[(size_t)r * N] = acc[m][n][r];
    }
  }
}

// ---------------- flash attention (R4-verified body; Q/K read from fused qkv) ----------------
// qkv: (B*2048, 3072) bf16 — Q cols rope'd+scaled, K cols rope'd.
// Vt: (B*KVH, 128, 2048) bf16.  Att: (B*2048, 2048) bf16.
__global__ __launch_bounds__(128, 3) void flash_attn(
    const u16* __restrict__ qkv, const u16* __restrict__ Vt, u16* __restrict__ Att) {
  __shared__ u16 Ks[2][32 * 128];   // 8KB/buf: 32 rows x 256B, slot ^= row&7
  __shared__ u16 Vs[2][128 * 32];   // 8KB/buf: 128 rows x 64B, slot ^= (row>>1)&3
  const int tid = threadIdx.x, lane = tid & 63, w = tid >> 6;
  const int lo = lane & 31, hi = lane >> 5;
  const int q0 = blockIdx.x * 64 + w * 32;
  const int h = blockIdx.y, b = blockIdx.z;
  const int kvh = h >> 2;

  // K head lives at qkv cols [2048 + kvh*128, +128); row stride 6144 B
  const char* Khead = (const char*)qkv + ((size_t)b * 2048 * 3072 + 2048 + kvh * 128) * 2;
  const char* Vhead = (const char*)(Vt + (size_t)(b * 4 + kvh) * 128 * 2048);

  // Q fragments (B-operand of swapped QK^T) straight from qkv
  bf16x8 qf[8];
  {
    const u16* qp = qkv + (size_t)(b * 2048 + q0 + lo) * 3072 + h * 128 + hi * 8;
#pragma unroll
    for (int ds = 0; ds < 8; ++ds) qf[ds] = *(const bf16x8*)(qp + ds * 16);
  }

#define STAGE(bufi, t)                                                        \
  {                                                                           \
    _Pragma("unroll")                                                         \
    for (int it = 0; it < 4; ++it) {                                          \
      int c = it * 128 + tid;                                                 \
      int krow = c >> 4;                                                      \
      int koff = ((c & 15) << 4) ^ ((krow & 7) << 4);                         \
      gload16(Khead + (size_t)((t) * 32 + krow) * 6144 + koff,                \
              (u16*)Ks[bufi] + it * 1024 + w * 512);                          \
      int vrow = c >> 2;                                                      \
      int voff = vrow * 4096 + ((c & 3) << 4 ^ (((vrow >> 1) & 3) << 4));     \
      gload16(Vhead + (size_t)(t) * 64 + voff,                                \
              (u16*)Vs[bufi] + it * 1024 + w * 512);                          \
    }                                                                         \
  }

  f32x16 o0 = {}, o1 = {}, o2 = {}, o3 = {};
  float m_run = -3.0e38f, l_run = 0.f;
  const int swz = (lo & 7) << 4;
  const int vswz = ((lo >> 1) & 3) << 4;
  const int hi16 = hi * 16;

  STAGE(0, 0);
  __syncthreads();

  int buf = 0;
  for (int t = 0; t < 64; ++t) {
    int tn = (t < 63) ? t + 1 : 63;
    STAGE(buf ^ 1, tn);

    const char* Kb = (const char*)Ks[buf];
    const char* Vb = (const char*)Vs[buf];

    // QK^T (swapped): lane holds S^T[key=crow(r,hi)][q=lo], keys 0..31 of tile
    f32x16 sc = {};
    __builtin_amdgcn_s_setprio(1);
#pragma unroll
    for (int ds = 0; ds < 8; ++ds) {
      bf16x8 kf = *(const bf16x8*)(Kb + lo * 256 + ((ds * 32 + hi16) ^ swz));
      sc = __builtin_amdgcn_mfma_f32_32x32x16_bf16(kf, qf[ds], sc, 0, 0, 0);
    }
    __builtin_amdgcn_s_setprio(0);

    // online softmax for q-row=lo (split across lane / lane^32): tree max
    float m01 = fmaxf(fmaxf(sc[0], sc[1]), fmaxf(sc[2], sc[3]));
    float m23 = fmaxf(fmaxf(sc[4], sc[5]), fmaxf(sc[6], sc[7]));
    float m45 = fmaxf(fmaxf(sc[8], sc[9]), fmaxf(sc[10], sc[11]));
    float m67 = fmaxf(fmaxf(sc[12], sc[13]), fmaxf(sc[14], sc[15]));
    float pmax = xmax32(fmaxf(fmaxf(m01, m23), fmaxf(m45, m67)));

    if (!__all(pmax - m_run <= 8.0f)) {   // T13 defer-max
      float mnew = fmaxf(m_run, pmax);
      float rs = __expf(m_run - mnew);
      m_run = mnew;
      l_run *= rs;
#pragma unroll
      for (int r = 0; r < 16; ++r) {
        float rsr = __shfl(rs, (r & 3) + 8 * (r >> 2) + 4 * hi, 64);
        o0[r] *= rsr; o1[r] *= rsr; o2[r] *= rsr; o3[r] *= rsr;
      }
    }

    float lsum = 0.f;
#pragma unroll
    for (int r = 0; r < 16; ++r) { float p = __expf(sc[r] - m_run); sc[r] = p; lsum += p; }
    l_run += xsum32(lsum);

    // repack P -> PV A-fragments via shfl_xor half-swap (HW-verified)
    bf16x8 pa0, pa1;
    {
      u32 a0 = pk(sc[0], sc[1]),   a1 = pk(sc[2], sc[3]);
      u32 b0 = pk(sc[4], sc[5]),   b1 = pk(sc[6], sc[7]);
      u32 t0 = hi ? a0 : b0, t1 = hi ? a1 : b1;
      u32 r0 = __shfl_xor(t0, 32, 64), r1 = __shfl_xor(t1, 32, 64);
      u32x4 w0;
      w0[0] = hi ? r0 : a0; w0[1] = hi ? r1 : a1;
      w0[2] = hi ? b0 : r0; w0[3] = hi ? b1 : r1;
      pa0 = __builtin_bit_cast(bf16x8, w0);
      u32 c0 = pk(sc[8], sc[9]),   c1 = pk(sc[10], sc[11]);
      u32 d0 = pk(sc[12], sc[13]), d1 = pk(sc[14], sc[15]);
      u32 t2 = hi ? c0 : d0, t3 = hi ? c1 : d1;
      u32 r2 = __shfl_xor(t2, 32, 64), r3 = __shfl_xor(t3, 32, 64);
      u32x4 w1;
      w1[0] = hi ? r2 : c0; w1[1] = hi ? r3 : c1;
      w1[2] = hi ? d0 : r2; w1[3] = hi ? d1 : r3;
      pa1 = __builtin_bit_cast(bf16x8, w1);
    }

    // PV: A = P[32q][32k], B = V[32k][128d] (from V^T tile, 64B rows)
    __builtin_amdgcn_s_setprio(1);
#define PVN(on, n)                                                                                     \
    {                                                                                                  \
      const char* vrb = Vb + ((n) * 32 + lo) * 64;                                                     \
      on = __builtin_amdgcn_mfma_f32_32x32x16_bf16(pa0, *(const bf16x8*)(vrb + ((0  + hi16) ^ vswz)), on, 0, 0, 0); \
      on = __builtin_amdgcn_mfma_f32_32x32x16_bf16(pa1, *(const bf16x8*)(vrb + ((32 + hi16) ^ vswz)), on, 0, 0, 0); \
    }
    PVN(o0, 0)
    PVN(o1, 1)
    PVN(o2, 2)
    PVN(o3, 3)
    __builtin_amdgcn_s_setprio(0);

    __syncthreads();
    buf ^= 1;
  }

  // epilogue: out rows = crow(r,hi), cols = n*32 + lo
  float inv = 1.0f / l_run;
  size_t rowbase = (size_t)(b * 2048 + q0);
#pragma unroll
  for (int r = 0; r < 16; ++r) {
    int rr = (r & 3) + 8 * (r >> 2) + 4 * hi;
    float invr = __shfl(inv, rr, 64);
    u16* op = Att + (rowbase + rr) * 2048 + h * 128 + lo;
    op[0]  = f2b(o0[r] * invr);
    op[32] = f2b(o1[r] * invr);
    op[64] = f2b(o2[r] * invr);
    op[96] = f2b(o3[r] * invr);
  }
}

// ---------------- launch ----------------

extern "C" void kernel_launch(void* const* d_in, const int* in_sizes, int n_in,
                              void* d_out, int out_size, void* d_ws, size_t ws_size,
                              hipStream_t stream) {
  const float* x  = (const float*)d_in[0];
  const float* wq = (const float*)d_in[1];
  const float* bq = (const float*)d_in[2];
  const float* wk = (const float*)d_in[3];
  const float* bk = (const float*)d_in[4];
  const float* wv = (const float*)d_in[5];
  const float* bv = (const float*)d_in[6];
  const float* wo = (const float*)d_in[7];
  float* out = (float*)d_out;
  char* ws = (char*)d_ws;

  // workspace layout (bytes); att overlays x_bf (dead after QKV GEMM)
  u16*   x_bf   = (u16*)  (ws + 0);            // 16,777,216
  u16*   att    = (u16*)  (ws + 0);            // reuse after gemm1
  u16*   wqkv_t = (u16*)  (ws + 16777216);     // 12,582,912
  u16*   wo_t   = (u16*)  (ws + 29360128);     //  8,388,608
  u16*   qkv    = (u16*)  (ws + 37761024);     // 25,165,824 (ends 62,926,848)
  u16*   v_t    = (u16*)  (ws + 109064192);    //  4,194,304  (end 113,258,496)

  // 1. converts
  cvt_f32_bf16<<<8192, 256, 0, stream>>>(x, x_bf, 2097152);
  w_transpose_all<<<dim3(64, 160), 256, 0, stream>>>(wq, wk, wv, wo, wqkv_t, wo_t);

  // 2. QKV projection + fused bias/RoPE/scale/V-transpose
  gemm256_bt<<<192, 512, 0, stream>>>(x_bf, wqkv_t, bq, bk, bv, qkv, v_t,
                                      4096, 3072, 2048, 12);

  // 3. flash attention -> att bf16 (Q/K from qkv, V from v_t)
  flash_attn<<<dim3(32, 16, 2), 128, 0, stream>>>(qkv, v_t, att);

  // 4. out projection: (4096 x 2048) @ (2048 x 2048) -> d_out fp32
  gemm128x256_bt<<<256, 512, 0, stream>>>(att, wo_t, out, 4096, 2048, 2048, 8);
}

// Round 14
// 255.336 us; speedup vs baseline: 1.0950x; 1.0950x over previous
//
#include <hip/hip_runtime.h>
#include <hip/hip_bf16.h>
#include <cstdint>

typedef __attribute__((ext_vector_type(4))) float f32x4;
typedef __attribute__((ext_vector_type(16))) float f32x16;
typedef __attribute__((ext_vector_type(8))) short bf16x8;
typedef __attribute__((ext_vector_type(4))) unsigned int u32x4;
typedef unsigned short u16;
typedef unsigned int u32;

__device__ __forceinline__ u16 f2b(float x) {
  __hip_bfloat16 h = __float2bfloat16(x);
  return *reinterpret_cast<u16*>(&h);
}

__device__ __forceinline__ float b2f(u32 u) {
  u32 v = u << 16;
  return __builtin_bit_cast(float, v);
}

__device__ __forceinline__ u32 pk(float a, float b) {
  __hip_bfloat162 h2 = __float22bfloat162_rn(float2{a, b});
  return *reinterpret_cast<u32*>(&h2);
}

__device__ __forceinline__ void gload16(const void* g, void* l) {
  __builtin_amdgcn_global_load_lds((const __attribute__((address_space(1))) u32*)g,
                                   (__attribute__((address_space(3))) u32*)l, 16, 0, 0);
}

__device__ __forceinline__ float xmax32(float x) {
  return fmaxf(x, __shfl_xor(x, 32, 64));
}
__device__ __forceinline__ float xsum32(float x) {
  return x + __shfl_xor(x, 32, 64);
}

// ---------------- converts ----------------

__global__ void cvt_f32_bf16(const float* __restrict__ in, u16* __restrict__ out, int n4) {
  int idx = (blockIdx.x * 256 + threadIdx.x);
  if (idx < n4) {
    const float4 v = *(const float4*)(in + (size_t)idx * 4);
    u16* o = out + (size_t)idx * 4;
    o[0] = f2b(v.x); o[1] = f2b(v.y); o[2] = f2b(v.z); o[3] = f2b(v.w);
  }
}

// merged: wq|wk|wv -> wqkv_t (by<96) and wo -> wo_t (by>=96)
__global__ void w_transpose_all(const float* __restrict__ wq, const float* __restrict__ wk,
                                const float* __restrict__ wv, const float* __restrict__ wo,
                                u16* __restrict__ wqkv_t, u16* __restrict__ wo_t) {
  __shared__ float tile[32][33];
  int k0 = blockIdx.x * 32;
  int by = blockIdx.y;
  const float* src; int srcN; int c0; u16* out; int n0;
  if (by < 96) {
    n0 = by * 32; out = wqkv_t;
    if (n0 < 2048)      { src = wq; srcN = 2048; c0 = n0; }
    else if (n0 < 2560) { src = wk; srcN = 512;  c0 = n0 - 2048; }
    else                { src = wv; srcN = 512;  c0 = n0 - 2560; }
  } else {
    n0 = (by - 96) * 32; out = wo_t; src = wo; srcN = 2048; c0 = n0;
  }
  int tx = threadIdx.x & 31, ty = threadIdx.x >> 5;
#pragma unroll
  for (int j = 0; j < 32; j += 8)
    tile[ty + j][tx] = src[(size_t)(k0 + ty + j) * srcN + c0 + tx];
  __syncthreads();
#pragma unroll
  for (int j = 0; j < 32; j += 8)
    out[(size_t)(n0 + ty + j) * 2048 + k0 + tx] = f2b(tile[tx][ty + j]);
}

// V slice of bf16 qkv -> transposed (B*KVH, 128, 2048)
__global__ void v_transpose_cvt(const u16* __restrict__ qkv, u16* __restrict__ vt) {
  __shared__ u16 tile[32][34];
  int s0 = blockIdx.x * 32;
  int d0 = blockIdx.y * 32;
  int z = blockIdx.z;              // b*4 + kvh
  int b = z >> 2, kvh = z & 3;
  int tx = threadIdx.x & 31, ty = threadIdx.x >> 5;
#pragma unroll
  for (int j = 0; j < 32; j += 8)
    tile[ty + j][tx] = qkv[((size_t)(b * 2048 + s0 + ty + j)) * 3072 + 2560 + kvh * 128 + d0 + tx];
  __syncthreads();
#pragma unroll
  for (int j = 0; j < 32; j += 8)
    vt[((size_t)z * 128 + d0 + ty + j) * 2048 + s0 + tx] = tile[tx][ty + j];
}

// ---------------- RoPE (bf16 in, bf16 out), Q and K merged in one launch ----------------
// flat pair index: [0, 4194304) -> Q (16 heads, scaled); [4194304, 5242880) -> K (4 heads).
__global__ void rope_cvt_qk(const u16* __restrict__ qkv, u16* __restrict__ q_r,
                            u16* __restrict__ k_r) {
  int idx = blockIdx.x * 256 + threadIdx.x;
  int lognh, col0; float scale; u16* out;
  if (idx < 4194304) {
    lognh = 4; col0 = 0; scale = 0.08838834764831845f; out = q_r;
  } else {
    idx -= 4194304;
    lognh = 2; col0 = 2048; scale = 1.0f; out = k_r;
  }
  int i = idx & 63;                            // pair within head
  int nh = 1 << lognh;
  int h = (idx >> 6) & (nh - 1);
  int bs = idx >> (6 + lognh);                 // 0..4095
  int s = bs & 2047;
  int b = bs >> 11;
  u32 pr = *(const u32*)(qkv + (size_t)bs * 3072 + col0 + h * 128 + 2 * i);
  float tr = b2f(pr & 0xffffu), ti = b2f(pr >> 16);
  float theta = expf(-(float)i * 0.14391156831212787f);  // ln(10000)/64
  float ang = (float)s * theta;
  float sv, cv;
  sincosf(ang, &sv, &cv);
  float orr = (tr * cv - ti * sv) * scale;
  float oii = (tr * sv + ti * cv) * scale;
  *(u32*)(out + (((size_t)(b * nh + h) * 2048 + s) * 128 + 2 * i)) = pk(orr, oii);
}

// ---------------- GEMM 256x256 8-phase (counted-vmcnt, K-half layout) ----------------
// QKV projection: C(bf16) = A @ Bt^T + bias(select from bq/bk/bv).
__global__ __launch_bounds__(512, 2) void gemm256_bt(
    const u16* __restrict__ A, const u16* __restrict__ Bt,
    const float* __restrict__ bq, const float* __restrict__ bk,
    const float* __restrict__ bv, u16* __restrict__ C,
    int M, int N, int K, int gx) {
  __shared__ u16 lds[65536];   // 131072 B
  const int tid = threadIdx.x, lane = tid & 63;
  const int w = tid >> 6, wr = w >> 2, wc = w & 3;
  const int nb = gridDim.x;
  const int swz = (blockIdx.x & 7) * (nb >> 3) + (blockIdx.x >> 3);
  const int m0 = (swz / gx) * 256, n0 = (swz % gx) * 256;
  const int l15 = lane & 15;
  const int gx16 = ((lane >> 4) * 16) ^ (((l15 >> 1) & 3) << 4);  // read byte-off (lane-const)

#define GL(X, kh, bufi, t)                                                      \
  { _Pragma("unroll")                                                           \
    for (int rd = 0; rd < 2; ++rd) {                                            \
      int c = tid + rd * 512;                                                   \
      int row = c >> 2;                                                         \
      int sx = ((c & 3) * 16) ^ (((row >> 1) & 3) << 4);                        \
      const u16* srcp = ((X) ? Bt + (size_t)(n0 + row) * K                      \
                             : A + (size_t)(m0 + row) * K) + (t) * 64 + (kh) * 32; \
      gload16((const char*)srcp + sx,                                           \
              (char*)lds + (bufi) * 65536 + (X) * 32768 + (kh) * 16384 + c * 16); \
    } }

  f32x4 acc[8][4] = {};
  const int NT = K >> 6;

  // prologue: tile 0, all 4 half-tiles -> buf0 (8 loads/thread outstanding)
  GL(0, 0, 0, 0) GL(1, 0, 0, 0) GL(0, 1, 0, 0) GL(1, 1, 0, 0)

  for (int t = 0; t < NT; ++t) {
    const int buf = t & 1, nbuf = buf ^ 1;
    const int tn = (t + 1 < NT) ? t + 1 : NT - 1;
    const char* Ab = (const char*)lds + buf * 65536;
    const char* Bb = Ab + 32768;
    bf16x8 af[4], bfr[4];

    // ---- phase 1: K-half 0, m0-3
    asm volatile("s_waitcnt vmcnt(4)" ::: "memory");
    __builtin_amdgcn_s_barrier();
    GL(0, 0, nbuf, tn)
#pragma unroll
    for (int n = 0; n < 4; ++n)
      bfr[n] = *(const bf16x8*)(Bb + (wc * 64 + n * 16 + l15) * 64 + gx16);
#pragma unroll
    for (int m = 0; m < 4; ++m)
      af[m] = *(const bf16x8*)(Ab + (wr * 128 + m * 16 + l15) * 64 + gx16);
    __builtin_amdgcn_s_setprio(1);
#pragma unroll
    for (int m = 0; m < 4; ++m)
#pragma unroll
      for (int n = 0; n < 4; ++n)
        acc[m][n] = __builtin_amdgcn_mfma_f32_16x16x32_bf16(af[m], bfr[n], acc[m][n], 0, 0, 0);
    __builtin_amdgcn_s_setprio(0);

    // ---- phase 2: K-half 0, m4-7
    GL(1, 0, nbuf, tn)
#pragma unroll
    for (int m = 0; m < 4; ++m)
      af[m] = *(const bf16x8*)(Ab + (wr * 128 + (m + 4) * 16 + l15) * 64 + gx16);
    __builtin_amdgcn_s_setprio(1);
#pragma unroll
    for (int m = 0; m < 4; ++m)
#pragma unroll
      for (int n = 0; n < 4; ++n)
        acc[m + 4][n] = __builtin_amdgcn_mfma_f32_16x16x32_bf16(af[m], bfr[n], acc[m + 4][n], 0, 0, 0);
    __builtin_amdgcn_s_setprio(0);

    // ---- phase 3: K-half 1, m0-3
    asm volatile("s_waitcnt vmcnt(4)" ::: "memory");
    __builtin_amdgcn_s_barrier();
    GL(0, 1, nbuf, tn)
#pragma unroll
    for (int n = 0; n < 4; ++n)
      bfr[n] = *(const bf16x8*)(Bb + 16384 + (wc * 64 + n * 16 + l15) * 64 + gx16);
#pragma unroll
    for (int m = 0; m < 4; ++m)
      af[m] = *(const bf16x8*)(Ab + 16384 + (wr * 128 + m * 16 + l15) * 64 + gx16);
    __builtin_amdgcn_s_setprio(1);
#pragma unroll
    for (int m = 0; m < 4; ++m)
#pragma unroll
      for (int n = 0; n < 4; ++n)
        acc[m][n] = __builtin_amdgcn_mfma_f32_16x16x32_bf16(af[m], bfr[n], acc[m][n], 0, 0, 0);
    __builtin_amdgcn_s_setprio(0);

    // ---- phase 4: K-half 1, m4-7
    GL(1, 1, nbuf, tn)
#pragma unroll
    for (int m = 0; m < 4; ++m)
      af[m] = *(const bf16x8*)(Ab + 16384 + (wr * 128 + (m + 4) * 16 + l15) * 64 + gx16);
    __builtin_amdgcn_s_setprio(1);
#pragma unroll
    for (int m = 0; m < 4; ++m)
#pragma unroll
      for (int n = 0; n < 4; ++n)
        acc[m + 4][n] = __builtin_amdgcn_mfma_f32_16x16x32_bf16(af[m], bfr[n], acc[m + 4][n], 0, 0, 0);
    __builtin_amdgcn_s_setprio(0);
  }
  asm volatile("s_waitcnt vmcnt(0)" ::: "memory");

  // epilogue (bf16 out, inline bias select)
#pragma unroll
  for (int m = 0; m < 8; ++m) {
    int row = m0 + wr * 128 + m * 16 + ((lane >> 4) << 2);
#pragma unroll
    for (int n = 0; n < 4; ++n) {
      int col = n0 + wc * 64 + n * 16 + l15;
      float bvv = (col < 2048) ? bq[col] : ((col < 2560) ? bk[col - 2048] : bv[col - 2560]);
      u16* cp = C + (size_t)row * N + col;
#pragma unroll
      for (int r = 0; r < 4; ++r) cp[(size_t)r * N] = f2b(acc[m][n][r] + bvv);
    }
  }
}

// ---------------- GEMM 128x256 2-phase (counted-vmcnt): out projection ----------------
__global__ __launch_bounds__(512, 1) void gemm128x256_bt(
    const u16* __restrict__ A, const u16* __restrict__ Bt,
    float* __restrict__ C, int M, int N, int K, int gx) {
  __shared__ u16 lds[49152];   // 98304 B
  const int tid = threadIdx.x, lane = tid & 63;
  const int w = tid >> 6, wr = w >> 2, wc = w & 3;
  const int nb = gridDim.x;
  const int swz = (blockIdx.x & 7) * (nb >> 3) + (blockIdx.x >> 3);
  const int m0 = (swz / gx) * 128, n0 = (swz % gx) * 256;
  const int l15 = lane & 15;
  const int gx16 = ((lane >> 4) * 16) ^ (((l15 >> 1) & 3) << 4);

#define GLA(kh, bufi, t)                                                        \
  { int c = tid;                                                                \
    int row = c >> 2;                                                           \
    int sx = ((c & 3) * 16) ^ (((row >> 1) & 3) << 4);                          \
    const u16* srcp = A + (size_t)(m0 + row) * K + (t) * 64 + (kh) * 32;        \
    gload16((const char*)srcp + sx,                                             \
            (char*)lds + (bufi) * 16384 + (kh) * 8192 + c * 16); }

#define GLB(kh, bufi, t)                                                        \
  { _Pragma("unroll")                                                           \
    for (int rd = 0; rd < 2; ++rd) {                                            \
      int c = tid + rd * 512;                                                   \
      int row = c >> 2;                                                         \
      int sx = ((c & 3) * 16) ^ (((row >> 1) & 3) << 4);                        \
      const u16* srcp = Bt + (size_t)(n0 + row) * K + (t) * 64 + (kh) * 32;     \
      gload16((const char*)srcp + sx,                                           \
              (char*)lds + 32768 + (bufi) * 32768 + (kh) * 16384 + c * 16); } }

  f32x4 acc[4][4] = {};
  const int NT = K >> 6;

  // prologue: tile 0, both K-halves (6 loads/thread outstanding)
  GLA(0, 0, 0) GLB(0, 0, 0) GLA(1, 0, 0) GLB(1, 0, 0)

  for (int t = 0; t < NT; ++t) {
    const int buf = t & 1, nbuf = buf ^ 1;
    const int tn = (t + 1 < NT) ? t + 1 : NT - 1;
    const char* Ab = (const char*)lds + buf * 16384;
    const char* Bb = (const char*)lds + 32768 + buf * 32768;
    bf16x8 af[4], bfr[4];

#pragma unroll
    for (int kh = 0; kh < 2; ++kh) {
      asm volatile("s_waitcnt vmcnt(3)" ::: "memory");
      __builtin_amdgcn_s_barrier();
      if (kh == 0) { GLA(0, nbuf, tn) GLB(0, nbuf, tn) }
      else         { GLA(1, nbuf, tn) GLB(1, nbuf, tn) }
#pragma unroll
      for (int n = 0; n < 4; ++n)
        bfr[n] = *(const bf16x8*)(Bb + kh * 16384 + (wc * 64 + n * 16 + l15) * 64 + gx16);
#pragma unroll
      for (int m = 0; m < 4; ++m)
        af[m] = *(const bf16x8*)(Ab + kh * 8192 + (wr * 64 + m * 16 + l15) * 64 + gx16);
      __builtin_amdgcn_s_setprio(1);
#pragma unroll
      for (int m = 0; m < 4; ++m)
#pragma unroll
        for (int n = 0; n < 4; ++n)
          acc[m][n] = __builtin_amdgcn_mfma_f32_16x16x32_bf16(af[m], bfr[n], acc[m][n], 0, 0, 0);
      __builtin_amdgcn_s_setprio(0);
    }
  }
  asm volatile("s_waitcnt vmcnt(0)" ::: "memory");

  // epilogue (f32 out, no bias)
#pragma unroll
  for (int m = 0; m < 4; ++m) {
    int row = m0 + wr * 64 + m * 16 + ((lane >> 4) << 2);
#pragma unroll
    for (int n = 0; n < 4; ++n) {
      int col = n0 + wc * 64 + n * 16 + l15;
      float* cp = C + (size_t)row * N + col;
#pragma unroll
      for (int r = 0; r < 4; ++r) cp[(size_t)r * N] = acc[m][n][r];
    }
  }
}

// ---------------- flash attention (R4-verified bytes) ----------------
__global__ __launch_bounds__(128, 3) void flash_attn(
    const u16* __restrict__ Qr, const u16* __restrict__ Kr,
    const u16* __restrict__ Vt, u16* __restrict__ Att) {
  __shared__ u16 Ks[2][32 * 128];   // 8KB/buf: 32 rows x 256B, slot ^= row&7
  __shared__ u16 Vs[2][128 * 32];   // 8KB/buf: 128 rows x 64B, slot ^= (row>>1)&3
  const int tid = threadIdx.x, lane = tid & 63, w = tid >> 6;
  const int lo = lane & 31, hi = lane >> 5;
  const int q0 = blockIdx.x * 64 + w * 32;
  const int h = blockIdx.y, b = blockIdx.z;
  const int kvh = h >> 2;

  const char* Khead = (const char*)(Kr + (size_t)(b * 4 + kvh) * 2048 * 128);
  const char* Vhead = (const char*)(Vt + (size_t)(b * 4 + kvh) * 128 * 2048);

  // Q fragments (B-operand of swapped QK^T)
  bf16x8 qf[8];
  {
    const u16* qp = Qr + ((size_t)(b * 16 + h) * 2048 + q0 + lo) * 128 + hi * 8;
#pragma unroll
    for (int ds = 0; ds < 8; ++ds) qf[ds] = *(const bf16x8*)(qp + ds * 16);
  }

#define STAGE(bufi, t)                                                        \
  {                                                                           \
    _Pragma("unroll")                                                         \
    for (int it = 0; it < 4; ++it) {                                          \
      int c = it * 128 + tid;                                                 \
      int krow = c >> 4;                                                      \
      int koff = krow * 256 + ((c & 15) << 4 ^ ((krow & 7) << 4));            \
      gload16(Khead + (size_t)(t) * 8192 + koff,                              \
              (u16*)Ks[bufi] + it * 1024 + w * 512);                          \
      int vrow = c >> 2;                                                      \
      int voff = vrow * 4096 + ((c & 3) << 4 ^ (((vrow >> 1) & 3) << 4));     \
      gload16(Vhead + (size_t)(t) * 64 + voff,                                \
              (u16*)Vs[bufi] + it * 1024 + w * 512);                          \
    }                                                                         \
  }

  f32x16 o0 = {}, o1 = {}, o2 = {}, o3 = {};
  float m_run = -3.0e38f, l_run = 0.f;
  const int swz = (lo & 7) << 4;
  const int vswz = ((lo >> 1) & 3) << 4;
  const int hi16 = hi * 16;

  STAGE(0, 0);
  __syncthreads();

  int buf = 0;
  for (int t = 0; t < 64; ++t) {
    int tn = (t < 63) ? t + 1 : 63;
    STAGE(buf ^ 1, tn);

    const char* Kb = (const char*)Ks[buf];
    const char* Vb = (const char*)Vs[buf];

    // QK^T (swapped): lane holds S^T[key=crow(r,hi)][q=lo], keys 0..31 of tile
    f32x16 sc = {};
    __builtin_amdgcn_s_setprio(1);
#pragma unroll
    for (int ds = 0; ds < 8; ++ds) {
      bf16x8 kf = *(const bf16x8*)(Kb + lo * 256 + ((ds * 32 + hi16) ^ swz));
      sc = __builtin_amdgcn_mfma_f32_32x32x16_bf16(kf, qf[ds], sc, 0, 0, 0);
    }
    __builtin_amdgcn_s_setprio(0);

    // online softmax for q-row=lo (split across lane / lane^32): tree max
    float m01 = fmaxf(fmaxf(sc[0], sc[1]), fmaxf(sc[2], sc[3]));
    float m23 = fmaxf(fmaxf(sc[4], sc[5]), fmaxf(sc[6], sc[7]));
    float m45 = fmaxf(fmaxf(sc[8], sc[9]), fmaxf(sc[10], sc[11]));
    float m67 = fmaxf(fmaxf(sc[12], sc[13]), fmaxf(sc[14], sc[15]));
    float pmax = xmax32(fmaxf(fmaxf(m01, m23), fmaxf(m45, m67)));

    if (!__all(pmax - m_run <= 8.0f)) {   // T13 defer-max
      float mnew = fmaxf(m_run, pmax);
      float rs = __expf(m_run - mnew);
      m_run = mnew;
      l_run *= rs;
#pragma unroll
      for (int r = 0; r < 16; ++r) {
        float rsr = __shfl(rs, (r & 3) + 8 * (r >> 2) + 4 * hi, 64);
        o0[r] *= rsr; o1[r] *= rsr; o2[r] *= rsr; o3[r] *= rsr;
      }
    }

    float lsum = 0.f;
#pragma unroll
    for (int r = 0; r < 16; ++r) { float p = __expf(sc[r] - m_run); sc[r] = p; lsum += p; }
    l_run += xsum32(lsum);

    // repack P -> PV A-fragments via shfl_xor half-swap (HW-verified)
    bf16x8 pa0, pa1;
    {
      u32 a0 = pk(sc[0], sc[1]),   a1 = pk(sc[2], sc[3]);
      u32 b0 = pk(sc[4], sc[5]),   b1 = pk(sc[6], sc[7]);
      u32 t0 = hi ? a0 : b0, t1 = hi ? a1 : b1;
      u32 r0 = __shfl_xor(t0, 32, 64), r1 = __shfl_xor(t1, 32, 64);
      u32x4 w0;
      w0[0] = hi ? r0 : a0; w0[1] = hi ? r1 : a1;
      w0[2] = hi ? b0 : r0; w0[3] = hi ? b1 : r1;
      pa0 = __builtin_bit_cast(bf16x8, w0);
      u32 c0 = pk(sc[8], sc[9]),   c1 = pk(sc[10], sc[11]);
      u32 d0 = pk(sc[12], sc[13]), d1 = pk(sc[14], sc[15]);
      u32 t2 = hi ? c0 : d0, t3 = hi ? c1 : d1;
      u32 r2 = __shfl_xor(t2, 32, 64), r3 = __shfl_xor(t3, 32, 64);
      u32x4 w1;
      w1[0] = hi ? r2 : c0; w1[1] = hi ? r3 : c1;
      w1[2] = hi ? d0 : r2; w1[3] = hi ? d1 : r3;
      pa1 = __builtin_bit_cast(bf16x8, w1);
    }

    // PV: A = P[32q][32k], B = V[32k][128d] (from V^T tile, 64B rows)
    __builtin_amdgcn_s_setprio(1);
#define PVN(on, n)                                                                                     \
    {                                                                                                  \
      const char* vrb = Vb + ((n) * 32 + lo) * 64;                                                     \
      on = __builtin_amdgcn_mfma_f32_32x32x16_bf16(pa0, *(const bf16x8*)(vrb + ((0  + hi16) ^ vswz)), on, 0, 0, 0); \
      on = __builtin_amdgcn_mfma_f32_32x32x16_bf16(pa1, *(const bf16x8*)(vrb + ((32 + hi16) ^ vswz)), on, 0, 0, 0); \
    }
    PVN(o0, 0)
    PVN(o1, 1)
    PVN(o2, 2)
    PVN(o3, 3)
    __builtin_amdgcn_s_setprio(0);

    __syncthreads();
    buf ^= 1;
  }

  // epilogue: out rows = crow(r,hi), cols = n*32 + lo
  float inv = 1.0f / l_run;
  size_t rowbase = (size_t)(b * 2048 + q0);
#pragma unroll
  for (int r = 0; r < 16; ++r) {
    int rr = (r & 3) + 8 * (r >> 2) + 4 * hi;
    float invr = __shfl(inv, rr, 64);
    u16* op = Att + (rowbase + rr) * 2048 + h * 128 + lo;
    op[0]  = f2b(o0[r] * invr);
    op[32] = f2b(o1[r] * invr);
    op[64] = f2b(o2[r] * invr);
    op[96] = f2b(o3[r] * invr);
  }
}

// ---------------- launch ----------------

extern "C" void kernel_launch(void* const* d_in, const int* in_sizes, int n_in,
                              void* d_out, int out_size, void* d_ws, size_t ws_size,
                              hipStream_t stream) {
  const float* x  = (const float*)d_in[0];
  const float* wq = (const float*)d_in[1];
  const float* bq = (const float*)d_in[2];
  const float* wk = (const float*)d_in[3];
  const float* bk = (const float*)d_in[4];
  const float* wv = (const float*)d_in[5];
  const float* bv = (const float*)d_in[6];
  const float* wo = (const float*)d_in[7];
  float* out = (float*)d_out;
  char* ws = (char*)d_ws;

  // workspace layout (bytes); att overlays x_bf (dead after QKV GEMM)
  u16*   x_bf   = (u16*)  (ws + 0);            // 16,777,216
  u16*   att    = (u16*)  (ws + 0);            // reuse after gemm1
  u16*   wqkv_t = (u16*)  (ws + 16777216);     // 12,582,912
  u16*   wo_t   = (u16*)  (ws + 29360128);     //  8,388,608
  u16*   qkv    = (u16*)  (ws + 37761024);     // 25,165,824 (ends 62,926,848)
  u16*   q_r    = (u16*)  (ws + 88092672);     // 16,777,216
  u16*   k_r    = (u16*)  (ws + 104869888);    //  4,194,304
  u16*   v_t    = (u16*)  (ws + 109064192);    //  4,194,304  (end 113,258,496)

  // 1. converts
  cvt_f32_bf16<<<8192, 256, 0, stream>>>(x, x_bf, 2097152);
  w_transpose_all<<<dim3(64, 160), 256, 0, stream>>>(wq, wk, wv, wo, wqkv_t, wo_t);

  // 2. QKV projection: (4096 x 2048) @ (2048 x 3072) + bias -> bf16  [256^2 counted-vmcnt]
  gemm256_bt<<<192, 512, 0, stream>>>(x_bf, wqkv_t, bq, bk, bv, qkv, 4096, 3072, 2048, 12);

  // 3. RoPE Q+K (merged launch, scale 1/sqrt(128) folded into Q); V transpose
  rope_cvt_qk<<<20480, 256, 0, stream>>>(qkv, q_r, k_r);
  v_transpose_cvt<<<dim3(64, 4, 8), 256, 0, stream>>>(qkv, v_t);

  // 4. flash attention -> att bf16
  flash_attn<<<dim3(32, 16, 2), 128, 0, stream>>>(q_r, k_r, v_t, att);

  // 5. out projection: (4096 x 2048) @ (2048 x 2048) -> d_out fp32  [128x256 counted-vmcnt]
  gemm128x256_bt<<<256, 512, 0, stream>>>(att, wo_t, out, 4096, 2048, 2048, 8);
}